// Round 1
// baseline (922.037 us; speedup 1.0000x reference)
//
#include <hip/hip_runtime.h>
#include <math.h>

static constexpr int C_IN = 32, IC = 4, H = 128, W = 128, G = 49, F = 196;
static constexpr int L = 1024, Q = 16384;
static constexpr float SCALE = 10.f;

// ---------------- K1: b1 = 3x3 conv (32->4, pad1), b2 = 1x1 conv (32->4) ----
__global__ __launch_bounds__(256) void k_front(
    const float* __restrict__ bsrc, const float* __restrict__ w_g, const float* __restrict__ b_g,
    const float* __restrict__ w_t, const float* __restrict__ b_t,
    float* __restrict__ b1, float* __restrict__ b2) {
  __shared__ float s_wg[IC*C_IN*9];
  __shared__ float s_wt[IC*C_IN];
  __shared__ float s_bg[IC], s_bt[IC];
  for (int i = threadIdx.x; i < IC*C_IN*9; i += 256) s_wg[i] = w_g[i];
  for (int i = threadIdx.x; i < IC*C_IN; i += 256) s_wt[i] = w_t[i];
  if (threadIdx.x < IC) { s_bg[threadIdx.x] = b_g[threadIdx.x]; s_bt[threadIdx.x] = b_t[threadIdx.x]; }
  __syncthreads();
  int idx = blockIdx.x*256 + threadIdx.x;          // 2*128*128 = 32768
  int x = idx & 127, y = (idx>>7) & 127, bb = idx >> 14;
  const float* bp = bsrc + (size_t)bb*C_IN*H*W;
  float a1[IC], a2[IC];
  #pragma unroll
  for (int o=0;o<IC;o++){ a1[o]=s_bg[o]; a2[o]=s_bt[o]; }
  for (int c=0;c<C_IN;c++){
    const float* bc = bp + c*H*W;
    float ctr = bc[y*W+x];
    #pragma unroll
    for (int o=0;o<IC;o++) a2[o] += ctr * s_wt[o*C_IN + c];
    #pragma unroll
    for (int dy=0; dy<3; dy++){
      int yy = y + dy - 1;
      if ((unsigned)yy >= (unsigned)H) continue;
      #pragma unroll
      for (int dx=0; dx<3; dx++){
        int xx = x + dx - 1;
        if ((unsigned)xx >= (unsigned)W) continue;
        float v = bc[yy*W+xx];
        #pragma unroll
        for (int o=0;o<IC;o++) a1[o] += v * s_wg[(o*C_IN + c)*9 + dy*3 + dx];
      }
    }
  }
  #pragma unroll
  for (int o=0;o<IC;o++){
    b1[((size_t)(bb*IC+o)*H + y)*W + x] = a1[o];
    b2[((size_t)(bb*IC+o)*H + y)*W + x] = a2[o];
  }
}

// ---------------- K2: xi[b][g][q] = relu(7x7x4->49 conv of b1, pad 3) -------
__global__ __launch_bounds__(128) void k_xi(
    const float* __restrict__ b1, const float* __restrict__ w_fc2, const float* __restrict__ b_fc2,
    float* __restrict__ xi) {
  __shared__ float s_w[G*F];
  __shared__ float s_b[G];
  __shared__ float s_p[IC*7*136];
  int tid = threadIdx.x;
  for (int i=tid;i<G*F;i+=128) s_w[i] = w_fc2[i];
  if (tid < G) s_b[tid] = b_fc2[tid];
  int bb = blockIdx.x >> 7, y = blockIdx.x & 127;
  for (int i=tid; i<IC*7*136; i+=128) {
    int col = i % 136; int t = i / 136; int ki = t % 7; int c = t / 7;
    int gy = y - 3 + ki, gx = col - 3;
    float v = 0.f;
    if ((unsigned)gy < (unsigned)H && (unsigned)gx < (unsigned)W && col < 134)
      v = b1[((size_t)(bb*IC+c)*H + gy)*W + gx];
    s_p[i] = v;
  }
  __syncthreads();
  int x = tid;
  float acc[G];
  #pragma unroll
  for (int g=0; g<G; g++) acc[g] = s_b[g];
  for (int c=0;c<IC;c++)
    for (int ki=0;ki<7;ki++){
      const float* prow = &s_p[(c*7+ki)*136 + x];
      #pragma unroll
      for (int kj=0;kj<7;kj++){
        float pv = prow[kj];
        int f = c*49 + ki*7 + kj;
        #pragma unroll
        for (int g=0; g<G; g++) acc[g] += pv * s_w[g*F + f];
      }
    }
  int q = y*W + x;
  float* xb = xi + (size_t)bb*G*Q;
  #pragma unroll
  for (int g=0; g<G; g++) xb[(size_t)g*Q + q] = fmaxf(acc[g], 0.f);
}

// ---------------- K3: meanxi[b][g] ------------------------------------------
__global__ __launch_bounds__(256) void k_meanxi(const float* __restrict__ xi, float* __restrict__ meanxi) {
  int blk = blockIdx.x;                       // bb*49+g, 0..97
  const float* src = xi + (size_t)blk*Q;
  float s = 0.f;
  for (int q = threadIdx.x; q < Q; q += 256) s += src[q];
  #pragma unroll
  for (int off=1; off<64; off<<=1) s += __shfl_xor(s, off);
  __shared__ float red[4];
  if ((threadIdx.x & 63) == 0) red[threadIdx.x>>6] = s;
  __syncthreads();
  if (threadIdx.x == 0) meanxi[blk] = (red[0]+red[1]+red[2]+red[3]) * (1.f/(float)Q);
}

// ---------------- K4: wi[b][p][g] = relu(7x7 stride4 conv of b1, pad(1,2)) --
__global__ __launch_bounds__(256) void k_wi(
    const float* __restrict__ b1, const float* __restrict__ w_fc1, const float* __restrict__ b_fc1,
    float* __restrict__ wi) {
  int i = blockIdx.x*256 + threadIdx.x;
  if (i >= 2*L*G) return;
  int g = i % G; int p = (i / G) % L; int bb = i / (G*L);
  int py = p >> 5, px = p & 31;
  float acc = b_fc1[g];
  const float* wrow = w_fc1 + (size_t)g*F;
  for (int c=0;c<IC;c++){
    const float* bc = b1 + (size_t)(bb*IC+c)*H*W;
    for (int ki=0;ki<7;ki++){
      int yy = py*4 - 1 + ki;
      if ((unsigned)yy >= (unsigned)H) continue;
      #pragma unroll
      for (int kj=0;kj<7;kj++){
        int xx = px*4 - 1 + kj;
        if ((unsigned)xx >= (unsigned)W) continue;
        acc += bc[yy*W+xx] * wrow[c*49 + ki*7 + kj];
      }
    }
  }
  wi[(size_t)(bb*L+p)*G + g] = fmaxf(acc, 0.f);
}

// ---------------- K5: thr[b,p], bias[b,p] (7x7x32 convs on b, stride 4) -----
__global__ __launch_bounds__(256) void k_thrbias(
    const float* __restrict__ bsrc, const float* __restrict__ w_thr, const float* __restrict__ b_thr,
    const float* __restrict__ w_bias, const float* __restrict__ b_bias,
    float* __restrict__ thr, float* __restrict__ bias) {
  int tid = threadIdx.x;
  int c = tid & 31, pl = tid >> 5;              // 8 p-positions x 32 channels
  int pg = blockIdx.x*8 + pl;                   // 0..2047
  int bb = pg >> 10, p = pg & 1023;
  int py = p >> 5, px = p & 31;
  const float* bc = bsrc + (size_t)(bb*C_IN + c)*H*W;
  float ta = 0.f, ba = 0.f;
  for (int ki=0;ki<7;ki++){
    int yy = py*4 - 1 + ki;
    if ((unsigned)yy >= (unsigned)H) continue;
    #pragma unroll
    for (int kj=0;kj<7;kj++){
      int xx = px*4 - 1 + kj;
      if ((unsigned)xx >= (unsigned)W) continue;
      float v = bc[yy*W+xx];
      ta += v * w_thr[c*49 + ki*7 + kj];
      ba += v * w_bias[c*49 + ki*7 + kj];
    }
  }
  #pragma unroll
  for (int off=1; off<32; off<<=1){ ta += __shfl_xor(ta, off); ba += __shfl_xor(ba, off); }
  if (c == 0) { thr[pg] = ta + b_thr[0]; bias[pg] = ba + b_bias[0]; }
}

// ---------------- K6: rowmean[b,p] = wi . meanxi ----------------------------
__global__ __launch_bounds__(256) void k_rowmean(
    const float* __restrict__ wi, const float* __restrict__ meanxi, float* __restrict__ rowmean){
  int i = blockIdx.x*256 + threadIdx.x;
  if (i >= 2*L) return;
  int bb = i >> 10;
  const float* wr = wi + (size_t)i*G;
  const float* mx = meanxi + bb*G;
  float s = 0.f;
  #pragma unroll
  for (int g=0; g<G; g++) s += wr[g]*mx[g];
  rowmean[i] = s;
}

// ---------------- K7: fused masked-softmax attention (flash-style) ----------
// 512 wgs = 2 q-halves x 2 batches x 128 p-tiles(8 rows). Online m/d per row.
__global__ __launch_bounds__(256) void k_attn(
    const float* __restrict__ b2, const float* __restrict__ xi, const float* __restrict__ wi,
    const float* __restrict__ thr, const float* __restrict__ bias, const float* __restrict__ rowmean,
    float* __restrict__ pacc, float* __restrict__ pm, float* __restrict__ pd) {
  __shared__ __align__(16) float sV[IC*8*136];
  __shared__ __align__(16) float sW[8][256];
  __shared__ __align__(16) float sWi[G][8];
  __shared__ float sRed[2][4][8];
  __shared__ float sCoef[8];
  int tid = threadIdx.x;
  int wid = blockIdx.x;
  int h = wid >> 8, bb = (wid >> 7) & 1, pt = wid & 127;
  for (int i=tid; i<8*G; i+=256){ int r = i / G, g = i % G; sWi[g][r] = wi[(size_t)(bb*L + pt*8 + r)*G + g]; }
  if (tid < 8) { int gi = bb*L + pt*8 + tid; sCoef[tid] = bias[gi] - rowmean[gi]*thr[gi]; }
  __syncthreads();
  float coef[8], m[8], d[8], acc[8];
  #pragma unroll
  for (int r=0;r<8;r++){ coef[r]=sCoef[r]; m[r]=-INFINITY; d[r]=0.f; acc[r]=0.f; }
  int fc = tid/49, fr_ = tid%49, fki = fr_/7, fkj = fr_%7;  // only used when tid<196
  const float* b2b = b2 + (size_t)bb*IC*H*W;
  const float* xib = xi + (size_t)bb*G*Q;
  for (int t=0; t<32; t++){
    int q0 = h*8192 + t*256;
    int y0 = q0 >> 7;
    __syncthreads();                                   // protect sV/sW reuse
    // stage V halo: b2 rows y0-3 .. y0+4 into [4][8][136] (zero-padded)
    for (int i=tid; i<IC*8*136; i+=256){
      int col = i % 136; int tt = i/136; int rr = tt & 7; int cc = tt >> 3;
      int gy = y0 - 3 + rr, gx = col - 3;
      float v = 0.f;
      if ((unsigned)gy < (unsigned)H && (unsigned)gx < (unsigned)W && col < 134)
        v = b2b[((size_t)cc*H + gy)*W + gx];
      sV[i] = v;
    }
    // phase A: scores for q = q0+tid against the 8 rows
    int q = q0 + tid;
    float s[8];
    #pragma unroll
    for (int r=0;r<8;r++) s[r] = 0.f;
    for (int g=0; g<G; g++){
      float xv = xib[(size_t)g*Q + q];
      float4 w0 = *(const float4*)&sWi[g][0];
      float4 w1 = *(const float4*)&sWi[g][4];
      s[0] += w0.x*xv; s[1] += w0.y*xv; s[2] += w0.z*xv; s[3] += w0.w*xv;
      s[4] += w1.x*xv; s[5] += w1.y*xv; s[6] += w1.z*xv; s[7] += w1.w*xv;
    }
    float st[8], mb[8], v[8];
    #pragma unroll
    for (int r=0;r<8;r++){
      float xm = s[r] + coef[r];
      mb[r] = (xm > 0.f) ? 1.f : 0.f;
      st[r] = s[r] * fmaxf(xm, 0.f) * SCALE;
      v[r] = st[r];
    }
    #pragma unroll
    for (int off=1; off<64; off<<=1){
      #pragma unroll
      for (int r=0;r<8;r++) v[r] = fmaxf(v[r], __shfl_xor(v[r], off));
    }
    int wv = tid >> 6;
    if ((tid & 63) == 0){
      #pragma unroll
      for (int r=0;r<8;r++) sRed[0][wv][r] = v[r];
    }
    __syncthreads();
    float mnew[8], e[8], alpha[8];
    #pragma unroll
    for (int r=0;r<8;r++){
      float t4 = fmaxf(fmaxf(sRed[0][0][r], sRed[0][1][r]), fmaxf(sRed[0][2][r], sRed[0][3][r]));
      mnew[r] = fmaxf(m[r], t4);
      alpha[r] = __expf(m[r] - mnew[r]);
      e[r] = __expf(st[r] - mnew[r]);                  // masked q: st=0 -> exp(-m), in denom
      sW[r][tid] = e[r]*mb[r];                         // numerator weight
      v[r] = e[r];
    }
    #pragma unroll
    for (int off=1; off<64; off<<=1){
      #pragma unroll
      for (int r=0;r<8;r++) v[r] += __shfl_xor(v[r], off);
    }
    if ((tid & 63) == 0){
      #pragma unroll
      for (int r=0;r<8;r++) sRed[1][wv][r] = v[r];
    }
    __syncthreads();
    #pragma unroll
    for (int r=0;r<8;r++){
      float ts = sRed[1][0][r]+sRed[1][1][r]+sRed[1][2][r]+sRed[1][3][r];
      d[r] = d[r]*alpha[r] + ts;
      m[r] = mnew[r];
    }
    // phase B: acc[r] += sum_q W[r][q] * V[q][f], thread owns f
    if (tid < 196){
      #pragma unroll
      for (int r=0;r<8;r++) acc[r] *= alpha[r];
      const float* vbase = &sV[(fc*8 + fki)*136 + fkj];
      #pragma unroll
      for (int yy=0; yy<2; yy++){
        const float* vrow = vbase + yy*136;
        for (int xx=0; xx<128; xx+=4){
          float v0=vrow[xx], v1=vrow[xx+1], v2=vrow[xx+2], v3=vrow[xx+3];
          int qq = yy*128 + xx;
          #pragma unroll
          for (int r=0;r<8;r++){
            float4 w4 = *(const float4*)&sW[r][qq];
            acc[r] += w4.x*v0; acc[r] += w4.y*v1; acc[r] += w4.z*v2; acc[r] += w4.w*v3;
          }
        }
      }
    }
  }
  if (tid < 196){
    #pragma unroll
    for (int r=0;r<8;r++) pacc[((size_t)wid*8 + r)*F + tid] = acc[r];
  }
  if (tid == 0){
    #pragma unroll
    for (int r=0;r<8;r++){ pm[wid*8+r] = m[r]; pd[wid*8+r] = d[r]; }
  }
}

// ---------------- K8: combine the two q-halves ------------------------------
__global__ __launch_bounds__(256) void k_combine(
    const float* __restrict__ pacc, const float* __restrict__ pm, const float* __restrict__ pd,
    float* __restrict__ outpf){
  int i = blockIdx.x*256 + threadIdx.x;
  if (i >= 2*L*F) return;
  int f = i % F; int p = (i/F) % L; int bb = i/(F*L);
  int pt = p >> 3, r = p & 7;
  int i0 = (bb*128 + pt)*8 + r;
  int i1 = (256 + bb*128 + pt)*8 + r;
  float m1 = pm[i0], m2 = pm[i1];
  float mm = fmaxf(m1, m2);
  float e1 = __expf(m1-mm), e2 = __expf(m2-mm);
  float num = e1*pacc[(size_t)i0*F + f] + e2*pacc[(size_t)i1*F + f];
  float den = e1*pd[i0] + e2*pd[i1];
  outpf[(size_t)(bb*L+p)*F + f] = num/den;
}

// ---------------- K9: fold + count-normalize --------------------------------
__global__ __launch_bounds__(256) void k_fold(const float* __restrict__ outpf, float* __restrict__ out){
  int i = blockIdx.x*256 + threadIdx.x;
  if (i >= 2*IC*H*W) return;
  int ww = i & 127, hh = (i>>7)&127, c = (i>>14)&3, bb = i>>16;
  int H3 = hh+3, W3 = ww+3;
  int py0 = (H3-3)>>2, py1 = min(31, H3>>2);
  int px0 = (W3-3)>>2, px1 = min(31, W3>>2);
  float s = 0.f; int cnt = 0;
  for (int py=py0; py<=py1; py++){
    int ki = H3 - 4*py;
    for (int px=px0; px<=px1; px++){
      int kj = W3 - 4*px;
      s += outpf[(size_t)((bb<<10) + py*32 + px)*F + c*49 + ki*7 + kj];
      cnt++;
    }
  }
  out[i] = s / (float)cnt;
}

extern "C" void kernel_launch(void* const* d_in, const int* in_sizes, int n_in,
                              void* d_out, int out_size, void* d_ws, size_t ws_size,
                              hipStream_t stream) {
  const float* b      = (const float*)d_in[0];
  const float* w_g    = (const float*)d_in[1];
  const float* b_g    = (const float*)d_in[2];
  const float* w_t    = (const float*)d_in[3];
  const float* b_t    = (const float*)d_in[4];
  const float* w_fc1  = (const float*)d_in[5];
  const float* b_fc1  = (const float*)d_in[6];
  const float* w_fc2  = (const float*)d_in[7];
  const float* b_fc2  = (const float*)d_in[8];
  const float* w_thr  = (const float*)d_in[9];
  const float* b_thr  = (const float*)d_in[10];
  const float* w_bias = (const float*)d_in[11];
  const float* b_bias = (const float*)d_in[12];
  float* out = (float*)d_out;
  float* ws = (float*)d_ws;

  float* b1      = ws;                 // 131072
  float* b2      = b1 + 131072;        // 131072
  float* xi      = b2 + 131072;        // 2*49*16384 = 1605632
  float* wi      = xi + 1605632;       // 100352
  float* meanxi  = wi + 100352;        // 128 (98 used)
  float* thr     = meanxi + 128;       // 2048
  float* bias    = thr + 2048;         // 2048
  float* rowmean = bias + 2048;        // 2048
  float* pacc    = rowmean + 2048;     // 512*8*196 = 802816
  float* pm      = pacc + 802816;      // 4096
  float* pd      = pm + 4096;          // 4096
  float* outpf   = pd + 4096;          // 401408
  (void)in_sizes; (void)n_in; (void)out_size; (void)ws_size;

  k_front  <<<128, 256, 0, stream>>>(b, w_g, b_g, w_t, b_t, b1, b2);
  k_xi     <<<256, 128, 0, stream>>>(b1, w_fc2, b_fc2, xi);
  k_meanxi <<<98,  256, 0, stream>>>(xi, meanxi);
  k_wi     <<<(2*L*G + 255)/256, 256, 0, stream>>>(b1, w_fc1, b_fc1, wi);
  k_thrbias<<<256, 256, 0, stream>>>(b, w_thr, b_thr, w_bias, b_bias, thr, bias);
  k_rowmean<<<8,   256, 0, stream>>>(wi, meanxi, rowmean);
  k_attn   <<<512, 256, 0, stream>>>(b2, xi, wi, thr, bias, rowmean, pacc, pm, pd);
  k_combine<<<(2*L*F + 255)/256, 256, 0, stream>>>(pacc, pm, pd, outpf);
  k_fold   <<<512, 256, 0, stream>>>(outpf, out);
}

// Round 2
// 471.399 us; speedup vs baseline: 1.9560x; 1.9560x over previous
//
#include <hip/hip_runtime.h>
#include <math.h>

static constexpr int C_IN = 32, IC = 4, H = 128, W = 128, G = 49, F = 196;
static constexpr int L = 1024, Q = 16384;
static constexpr float SCALE = 10.f;
static constexpr int NH = 8;       // q-splits
static constexpr int QT = 1024;    // q-tile per online iter
static constexpr int ITERS = 2;    // q-chunk = 2048 per block
static constexpr int B2P_PER_B = 4*5*136*136;  // 369920 bf16 elems per batch

typedef __attribute__((ext_vector_type(8))) short short8;
typedef __attribute__((ext_vector_type(4))) float floatx4;

__device__ __forceinline__ unsigned short f2bf(float f){
  unsigned u = __float_as_uint(f);
  return (unsigned short)((u + 0x7fffu + ((u >> 16) & 1u)) >> 16);
}

// ---------------- K1: b1 = 3x3 conv (32->4, pad1), b2 = 1x1 conv (32->4) ----
__global__ __launch_bounds__(256) void k_front(
    const float* __restrict__ bsrc, const float* __restrict__ w_g, const float* __restrict__ b_g,
    const float* __restrict__ w_t, const float* __restrict__ b_t,
    float* __restrict__ b1, float* __restrict__ b2) {
  __shared__ float s_wg[IC*C_IN*9];
  __shared__ float s_wt[IC*C_IN];
  __shared__ float s_bg[IC], s_bt[IC];
  for (int i = threadIdx.x; i < IC*C_IN*9; i += 256) s_wg[i] = w_g[i];
  for (int i = threadIdx.x; i < IC*C_IN; i += 256) s_wt[i] = w_t[i];
  if (threadIdx.x < IC) { s_bg[threadIdx.x] = b_g[threadIdx.x]; s_bt[threadIdx.x] = b_t[threadIdx.x]; }
  __syncthreads();
  int idx = blockIdx.x*256 + threadIdx.x;
  int x = idx & 127, y = (idx>>7) & 127, bb = idx >> 14;
  const float* bp = bsrc + (size_t)bb*C_IN*H*W;
  float a1[IC], a2[IC];
  #pragma unroll
  for (int o=0;o<IC;o++){ a1[o]=s_bg[o]; a2[o]=s_bt[o]; }
  for (int c=0;c<C_IN;c++){
    const float* bc = bp + c*H*W;
    float ctr = bc[y*W+x];
    #pragma unroll
    for (int o=0;o<IC;o++) a2[o] += ctr * s_wt[o*C_IN + c];
    #pragma unroll
    for (int dy=0; dy<3; dy++){
      int yy = y + dy - 1;
      if ((unsigned)yy >= (unsigned)H) continue;
      #pragma unroll
      for (int dx=0; dx<3; dx++){
        int xx = x + dx - 1;
        if ((unsigned)xx >= (unsigned)W) continue;
        float v = bc[yy*W+xx];
        #pragma unroll
        for (int o=0;o<IC;o++) a1[o] += v * s_wg[(o*C_IN + c)*9 + dy*3 + dx];
      }
    }
  }
  #pragma unroll
  for (int o=0;o<IC;o++){
    b1[((size_t)(bb*IC+o)*H + y)*W + x] = a1[o];
    b2[((size_t)(bb*IC+o)*H + y)*W + x] = a2[o];
  }
}

// ---------------- K1b: build 4 x-shifted zero-padded bf16 copies of b2 ------
// b2p[bb][s][c][ry][u] = b2[bb][c][ry-3][u+s-3], zero out-of-range or c==4.
__global__ __launch_bounds__(256) void k_prep(
    const float* __restrict__ b2, unsigned short* __restrict__ b2p) {
  int i = blockIdx.x*256 + threadIdx.x;
  if (i >= 2*B2P_PER_B) return;
  int bb = i / B2P_PER_B;
  int r = i % B2P_PER_B;
  int s = r / (5*136*136);
  int r2 = r % (5*136*136);
  int c = r2 / (136*136);
  int r3 = r2 % (136*136);
  int ry = r3 / 136, u = r3 % 136;
  int gy = ry - 3, gx = u + s - 3;
  float v = 0.f;
  if (c < 4 && (unsigned)gy < (unsigned)H && (unsigned)gx < (unsigned)W)
    v = b2[((size_t)(bb*IC + c)*H + gy)*W + gx];
  b2p[i] = f2bf(v);
}

// ---------------- K2: xi[b][g][q] = relu(7x7x4->49 conv of b1, pad 3) -------
__global__ __launch_bounds__(128) void k_xi(
    const float* __restrict__ b1, const float* __restrict__ w_fc2, const float* __restrict__ b_fc2,
    float* __restrict__ xi) {
  __shared__ float s_w[G*F];
  __shared__ float s_b[G];
  __shared__ float s_p[IC*7*136];
  int tid = threadIdx.x;
  for (int i=tid;i<G*F;i+=128) s_w[i] = w_fc2[i];
  if (tid < G) s_b[tid] = b_fc2[tid];
  int bb = blockIdx.x >> 7, y = blockIdx.x & 127;
  for (int i=tid; i<IC*7*136; i+=128) {
    int col = i % 136; int t = i / 136; int ki = t % 7; int c = t / 7;
    int gy = y - 3 + ki, gx = col - 3;
    float v = 0.f;
    if ((unsigned)gy < (unsigned)H && (unsigned)gx < (unsigned)W && col < 134)
      v = b1[((size_t)(bb*IC+c)*H + gy)*W + gx];
    s_p[i] = v;
  }
  __syncthreads();
  int x = tid;
  float acc[G];
  #pragma unroll
  for (int g=0; g<G; g++) acc[g] = s_b[g];
  for (int c=0;c<IC;c++)
    for (int ki=0;ki<7;ki++){
      const float* prow = &s_p[(c*7+ki)*136 + x];
      #pragma unroll
      for (int kj=0;kj<7;kj++){
        float pv = prow[kj];
        int f = c*49 + ki*7 + kj;
        #pragma unroll
        for (int g=0; g<G; g++) acc[g] += pv * s_w[g*F + f];
      }
    }
  int q = y*W + x;
  float* xb = xi + (size_t)bb*G*Q;
  #pragma unroll
  for (int g=0; g<G; g++) xb[(size_t)g*Q + q] = fmaxf(acc[g], 0.f);
}

// ---------------- K3: meanxi[b][g] ------------------------------------------
__global__ __launch_bounds__(256) void k_meanxi(const float* __restrict__ xi, float* __restrict__ meanxi) {
  int blk = blockIdx.x;
  const float* src = xi + (size_t)blk*Q;
  float s = 0.f;
  for (int q = threadIdx.x; q < Q; q += 256) s += src[q];
  #pragma unroll
  for (int off=1; off<64; off<<=1) s += __shfl_xor(s, off);
  __shared__ float red[4];
  if ((threadIdx.x & 63) == 0) red[threadIdx.x>>6] = s;
  __syncthreads();
  if (threadIdx.x == 0) meanxi[blk] = (red[0]+red[1]+red[2]+red[3]) * (1.f/(float)Q);
}

// ---------------- K4: wi[b][p][g] -------------------------------------------
__global__ __launch_bounds__(256) void k_wi(
    const float* __restrict__ b1, const float* __restrict__ w_fc1, const float* __restrict__ b_fc1,
    float* __restrict__ wi) {
  int i = blockIdx.x*256 + threadIdx.x;
  if (i >= 2*L*G) return;
  int g = i % G; int p = (i / G) % L; int bb = i / (G*L);
  int py = p >> 5, px = p & 31;
  float acc = b_fc1[g];
  const float* wrow = w_fc1 + (size_t)g*F;
  for (int c=0;c<IC;c++){
    const float* bc = b1 + (size_t)(bb*IC+c)*H*W;
    for (int ki=0;ki<7;ki++){
      int yy = py*4 - 1 + ki;
      if ((unsigned)yy >= (unsigned)H) continue;
      #pragma unroll
      for (int kj=0;kj<7;kj++){
        int xx = px*4 - 1 + kj;
        if ((unsigned)xx >= (unsigned)W) continue;
        acc += bc[yy*W+xx] * wrow[c*49 + ki*7 + kj];
      }
    }
  }
  wi[(size_t)(bb*L+p)*G + g] = fmaxf(acc, 0.f);
}

// ---------------- K5: thr[b,p], bias[b,p] -----------------------------------
__global__ __launch_bounds__(256) void k_thrbias(
    const float* __restrict__ bsrc, const float* __restrict__ w_thr, const float* __restrict__ b_thr,
    const float* __restrict__ w_bias, const float* __restrict__ b_bias,
    float* __restrict__ thr, float* __restrict__ bias) {
  int tid = threadIdx.x;
  int c = tid & 31, pl = tid >> 5;
  int pg = blockIdx.x*8 + pl;
  int bb = pg >> 10, p = pg & 1023;
  int py = p >> 5, px = p & 31;
  const float* bc = bsrc + (size_t)(bb*C_IN + c)*H*W;
  float ta = 0.f, ba = 0.f;
  for (int ki=0;ki<7;ki++){
    int yy = py*4 - 1 + ki;
    if ((unsigned)yy >= (unsigned)H) continue;
    #pragma unroll
    for (int kj=0;kj<7;kj++){
      int xx = px*4 - 1 + kj;
      if ((unsigned)xx >= (unsigned)W) continue;
      float v = bc[yy*W+xx];
      ta += v * w_thr[c*49 + ki*7 + kj];
      ba += v * w_bias[c*49 + ki*7 + kj];
    }
  }
  #pragma unroll
  for (int off=1; off<32; off<<=1){ ta += __shfl_xor(ta, off); ba += __shfl_xor(ba, off); }
  if (c == 0) { thr[pg] = ta + b_thr[0]; bias[pg] = ba + b_bias[0]; }
}

// ---------------- K6: rowmean[b,p] = wi . meanxi ----------------------------
__global__ __launch_bounds__(256) void k_rowmean(
    const float* __restrict__ wi, const float* __restrict__ meanxi, float* __restrict__ rowmean){
  int i = blockIdx.x*256 + threadIdx.x;
  if (i >= 2*L) return;
  int bb = i >> 10;
  const float* wr = wi + (size_t)i*G;
  const float* mx = meanxi + bb*G;
  float s = 0.f;
  #pragma unroll
  for (int g=0; g<G; g++) s += wr[g]*mx[g];
  rowmean[i] = s;
}

// ---------------- K7: fused attention: fp32 scores + bf16 MFMA PV -----------
// grid = 2 bb x 64 ptile(16 rows) x 8 q-splits. Block: 256 thr (4 waves).
// wave: rg=wave>>1 owns rows rg*8..+7, qh=wave&1 owns q-half of the 1024 tile.
__global__ __launch_bounds__(256) void k_attn(
    const unsigned short* __restrict__ b2p, const float* __restrict__ xi, const float* __restrict__ wi,
    const float* __restrict__ thr, const float* __restrict__ bias, const float* __restrict__ rowmean,
    float* __restrict__ pacc, float* __restrict__ pm, float* __restrict__ pd) {
  __shared__ float sWi[G][16];
  __shared__ unsigned short sWu[16*1032];       // W tile bf16, padded stride
  __shared__ float sMax[4][8], sSum[4][8], sAlpha[16], sCoef[16];
  int tid = threadIdx.x, lane = tid & 63, wave = tid >> 6;
  int wid = blockIdx.x;
  int h = wid & 7, pt = (wid >> 3) & 63, bb = wid >> 9;
  int rg = wave >> 1, qh = wave & 1, R0 = rg*8;
  for (int i=tid; i<G*16; i+=256){ int g = i>>4, r = i&15; sWi[g][r] = wi[(size_t)(bb*L + pt*16 + r)*G + g]; }
  if (tid < 16){ int gi = bb*L + pt*16 + tid; sCoef[tid] = bias[gi] - rowmean[gi]*thr[gi]; }
  __syncthreads();
  float cf[8];
  #pragma unroll
  for (int r=0;r<8;r++) cf[r] = sCoef[R0+r];
  float m[8], d[8];
  #pragma unroll
  for (int r=0;r<8;r++){ m[r] = -INFINITY; d[r] = 0.f; }
  floatx4 acc[4];
  #pragma unroll
  for (int i=0;i<4;i++) acc[i] = (floatx4){0.f,0.f,0.f,0.f};
  int l16 = lane & 15, lg = lane >> 4;
  int ts = (wave*13) >> 2, te = ((wave+1)*13) >> 2;
  int At[4], storeok[4];
  #pragma unroll
  for (int i=0;i<4;i++){
    int tile = ts + i; storeok[i] = (tile < te); if (tile > 12) tile = 12;
    int f = tile*16 + l16;
    int fc = f/49, rem = f%49, fki = rem/7, fkj = rem%7;
    int sft = fkj & 3, u4 = fkj & 4;
    At[i] = ((sft*5 + fc)*136 + fki)*136 + u4;
  }
  const float* xib = xi + (size_t)bb*G*Q;
  int bbase = bb * B2P_PER_B;
  for (int t=0; t<ITERS; t++){
    int q0 = h*(ITERS*QT) + t*QT;
    int qb = q0 + qh*512 + lane*8;
    float s[8][8];
    #pragma unroll
    for (int r=0;r<8;r++)
      #pragma unroll
      for (int j=0;j<8;j++) s[r][j] = 0.f;
    for (int g=0; g<G; g++){
      float4 xa = *(const float4*)&xib[(size_t)g*Q + qb];
      float4 xb2 = *(const float4*)&xib[(size_t)g*Q + qb + 4];
      float4 w0 = *(const float4*)&sWi[g][R0];
      float4 w1 = *(const float4*)&sWi[g][R0+4];
      float xs[8] = {xa.x,xa.y,xa.z,xa.w,xb2.x,xb2.y,xb2.z,xb2.w};
      float wv[8] = {w0.x,w0.y,w0.z,w0.w,w1.x,w1.y,w1.z,w1.w};
      #pragma unroll
      for (int r=0;r<8;r++)
        #pragma unroll
        for (int j=0;j<8;j++) s[r][j] += wv[r]*xs[j];
    }
    unsigned mbits[8];
    float mx[8];
    #pragma unroll
    for (int r=0;r<8;r++){
      mbits[r] = 0u; mx[r] = 0.f;
      #pragma unroll
      for (int j=0;j<8;j++){
        float xm = s[r][j] + cf[r];
        if (xm > 0.f) mbits[r] |= (1u<<j);
        float st = s[r][j] * fmaxf(xm, 0.f) * SCALE;
        s[r][j] = st;
        mx[r] = fmaxf(mx[r], st);
      }
    }
    #pragma unroll
    for (int off=1; off<64; off<<=1){
      #pragma unroll
      for (int r=0;r<8;r++) mx[r] = fmaxf(mx[r], __shfl_xor(mx[r], off));
    }
    if (lane == 0){
      #pragma unroll
      for (int r=0;r<8;r++) sMax[wave][r] = mx[r];
    }
    __syncthreads();
    float al[8], sum[8];
    #pragma unroll
    for (int r=0;r<8;r++){
      float mn = fmaxf(m[r], fmaxf(sMax[2*rg][r], sMax[2*rg+1][r]));
      al[r] = __expf(m[r] - mn);
      m[r] = mn;
    }
    #pragma unroll
    for (int r=0;r<8;r++){
      float e[8];
      float sr = 0.f;
      #pragma unroll
      for (int j=0;j<8;j++){ e[j] = __expf(s[r][j] - m[r]); sr += e[j]; }
      sum[r] = sr;
      unsigned pk[4];
      #pragma unroll
      for (int jj=0;jj<4;jj++){
        unsigned lo = ((mbits[r]>>(2*jj))&1u)   ? (unsigned)f2bf(e[2*jj])   : 0u;
        unsigned hi = ((mbits[r]>>(2*jj+1))&1u) ? (unsigned)f2bf(e[2*jj+1]) : 0u;
        pk[jj] = lo | (hi << 16);
      }
      uint4 pv = {pk[0], pk[1], pk[2], pk[3]};
      *(uint4*)&sWu[(R0+r)*1032 + qh*512 + lane*8] = pv;
    }
    #pragma unroll
    for (int off=1; off<64; off<<=1){
      #pragma unroll
      for (int r=0;r<8;r++) sum[r] += __shfl_xor(sum[r], off);
    }
    if (lane == 0){
      #pragma unroll
      for (int r=0;r<8;r++) sSum[wave][r] = sum[r];
    }
    if (qh == 0 && lane == 0){
      #pragma unroll
      for (int r=0;r<8;r++) sAlpha[R0+r] = al[r];
    }
    __syncthreads();
    #pragma unroll
    for (int r=0;r<8;r++) d[r] = d[r]*al[r] + sSum[2*rg][r] + sSum[2*rg+1][r];
    // phase B: MFMA over 32 k-steps
    floatx4 av = { sAlpha[lg*4+0], sAlpha[lg*4+1], sAlpha[lg*4+2], sAlpha[lg*4+3] };
    #pragma unroll
    for (int i=0;i<4;i++) acc[i] *= av;
    int ybase = q0 >> 7;
    for (int k0=0; k0<QT; k0+=32){
      int kk = k0 + lg*8;
      int y = ybase + (kk >> 7), x8 = kk & 127;
      uint4 avv = *(const uint4*)&sWu[l16*1032 + kk];
      short8 afr = *(short8*)&avv;
      int gb = bbase + y*136 + x8;
      #pragma unroll
      for (int i=0;i<4;i++){
        const unsigned short* p = b2p + gb + At[i];
        uint2 lo = *(const uint2*)p;
        uint2 hi = *(const uint2*)(p + 4);
        uint4 bv = {lo.x, lo.y, hi.x, hi.y};
        short8 bfr = *(short8*)&bv;
        acc[i] = __builtin_amdgcn_mfma_f32_16x16x32_bf16(afr, bfr, acc[i], 0, 0, 0);
      }
    }
  }
  int pbase = ((bb*64 + pt)*8 + h)*16;
  #pragma unroll
  for (int i=0;i<4;i++){
    int f = (ts+i)*16 + l16;
    if (storeok[i] && f < F){
      #pragma unroll
      for (int j=0;j<4;j++)
        pacc[(size_t)(pbase + lg*4 + j)*F + f] = acc[i][j];
    }
  }
  if (qh == 0 && lane == 0){
    #pragma unroll
    for (int r=0;r<8;r++){ pm[pbase + R0 + r] = m[r]; pd[pbase + R0 + r] = d[r]; }
  }
}

// ---------------- K8: combine the 8 q-splits --------------------------------
__global__ __launch_bounds__(256) void k_combine(
    const float* __restrict__ pacc, const float* __restrict__ pm, const float* __restrict__ pd,
    float* __restrict__ outpf){
  int i = blockIdx.x*256 + threadIdx.x;
  if (i >= 2*L*F) return;
  int f = i % F; int p = (i/F) % L; int bb = i/(F*L);
  int pt = p >> 4, row = p & 15;
  int base = ((bb*64 + pt)*8)*16 + row;
  float M = -INFINITY;
  #pragma unroll
  for (int hh=0; hh<NH; hh++) M = fmaxf(M, pm[base + hh*16]);
  float num = 0.f, den = 0.f;
  #pragma unroll
  for (int hh=0; hh<NH; hh++){
    float e = __expf(pm[base + hh*16] - M);
    num += e * pacc[(size_t)(base + hh*16)*F + f];
    den += e * pd[base + hh*16];
  }
  outpf[(size_t)(bb*L + p)*F + f] = num/den;
}

// ---------------- K9: fold + count-normalize --------------------------------
__global__ __launch_bounds__(256) void k_fold(const float* __restrict__ outpf, float* __restrict__ out){
  int i = blockIdx.x*256 + threadIdx.x;
  if (i >= 2*IC*H*W) return;
  int ww = i & 127, hh = (i>>7)&127, c = (i>>14)&3, bb = i>>16;
  int H3 = hh+3, W3 = ww+3;
  int py0 = (H3-3)>>2, py1 = min(31, H3>>2);
  int px0 = (W3-3)>>2, px1 = min(31, W3>>2);
  float s = 0.f; int cnt = 0;
  for (int py=py0; py<=py1; py++){
    int ki = H3 - 4*py;
    for (int px=px0; px<=px1; px++){
      int kj = W3 - 4*px;
      s += outpf[(size_t)((bb<<10) + py*32 + px)*F + c*49 + ki*7 + kj];
      cnt++;
    }
  }
  out[i] = s / (float)cnt;
}

extern "C" void kernel_launch(void* const* d_in, const int* in_sizes, int n_in,
                              void* d_out, int out_size, void* d_ws, size_t ws_size,
                              hipStream_t stream) {
  const float* b      = (const float*)d_in[0];
  const float* w_g    = (const float*)d_in[1];
  const float* b_g    = (const float*)d_in[2];
  const float* w_t    = (const float*)d_in[3];
  const float* b_t    = (const float*)d_in[4];
  const float* w_fc1  = (const float*)d_in[5];
  const float* b_fc1  = (const float*)d_in[6];
  const float* w_fc2  = (const float*)d_in[7];
  const float* b_fc2  = (const float*)d_in[8];
  const float* w_thr  = (const float*)d_in[9];
  const float* b_thr  = (const float*)d_in[10];
  const float* w_bias = (const float*)d_in[11];
  const float* b_bias = (const float*)d_in[12];
  float* out = (float*)d_out;
  float* ws = (float*)d_ws;

  float* b1      = ws;                       // 131072
  float* b2      = b1 + 131072;              // 131072
  float* xi      = b2 + 131072;              // 1605632
  float* wi      = xi + 1605632;             // 100352
  float* meanxi  = wi + 100352;              // 128
  float* thr     = meanxi + 128;             // 2048
  float* bias    = thr + 2048;               // 2048
  float* rowmean = bias + 2048;              // 2048
  unsigned short* b2p = (unsigned short*)(rowmean + 2048);  // 739840 u16 = 369920 f32
  float* pacc    = rowmean + 2048 + 369920;  // 1024*16*196 = 3211264
  float* pm      = pacc + 3211264;           // 16384
  float* pd      = pm + 16384;               // 16384
  float* outpf   = pd + 16384;               // 401408
  (void)in_sizes; (void)n_in; (void)out_size; (void)ws_size;

  k_front  <<<128, 256, 0, stream>>>(b, w_g, b_g, w_t, b_t, b1, b2);
  k_prep   <<<(2*B2P_PER_B + 255)/256, 256, 0, stream>>>(b2, b2p);
  k_xi     <<<256, 128, 0, stream>>>(b1, w_fc2, b_fc2, xi);
  k_meanxi <<<98,  256, 0, stream>>>(xi, meanxi);
  k_wi     <<<(2*L*G + 255)/256, 256, 0, stream>>>(b1, w_fc1, b_fc1, wi);
  k_thrbias<<<256, 256, 0, stream>>>(b, w_thr, b_thr, w_bias, b_bias, thr, bias);
  k_rowmean<<<8,   256, 0, stream>>>(wi, meanxi, rowmean);
  k_attn   <<<1024, 256, 0, stream>>>(b2p, xi, wi, thr, bias, rowmean, pacc, pm, pd);
  k_combine<<<(2*L*F + 255)/256, 256, 0, stream>>>(pacc, pm, pd, outpf);
  k_fold   <<<512, 256, 0, stream>>>(outpf, out);
}

// Round 4
// 406.191 us; speedup vs baseline: 2.2700x; 1.1605x over previous
//
#include <hip/hip_runtime.h>
#include <hip/hip_fp16.h>
#include <math.h>

static constexpr int C_IN = 32, IC = 4, H = 128, W = 128, G = 49, F = 196;
static constexpr int L = 1024, Q = 16384;
static constexpr float SCALE = 10.f;
static constexpr int NH = 8;       // q-splits (2048 q each, 2 online tiles of 1024)
static constexpr int B2P_PER_B = 4*5*136*136;  // 369920 bf16 elems per batch

typedef __attribute__((ext_vector_type(8))) short short8;
typedef __attribute__((ext_vector_type(4))) float floatx4;

__device__ __forceinline__ unsigned short f2bf(float f){
  unsigned u = __float_as_uint(f);
  return (unsigned short)((u + 0x7fffu + ((u >> 16) & 1u)) >> 16);
}
__device__ __forceinline__ float bf2f(unsigned short h){
  return __uint_as_float(((unsigned)h) << 16);
}
__device__ __forceinline__ floatx4 mfma16(uint4 a, uint4 b, floatx4 c){
  return __builtin_amdgcn_mfma_f32_16x16x32_bf16(*(short8*)&a, *(short8*)&b, c, 0, 0, 0);
}

// ---------------- K1: b1 = 3x3 conv (32->4, pad1), b2 = 1x1 conv (32->4) ----
__global__ __launch_bounds__(256) void k_front(
    const float* __restrict__ bsrc, const float* __restrict__ w_g, const float* __restrict__ b_g,
    const float* __restrict__ w_t, const float* __restrict__ b_t,
    float* __restrict__ b1, float* __restrict__ b2) {
  __shared__ float s_wg[IC*C_IN*9];
  __shared__ float s_wt[IC*C_IN];
  __shared__ float s_bg[IC], s_bt[IC];
  for (int i = threadIdx.x; i < IC*C_IN*9; i += 256) s_wg[i] = w_g[i];
  for (int i = threadIdx.x; i < IC*C_IN; i += 256) s_wt[i] = w_t[i];
  if (threadIdx.x < IC) { s_bg[threadIdx.x] = b_g[threadIdx.x]; s_bt[threadIdx.x] = b_t[threadIdx.x]; }
  __syncthreads();
  int idx = blockIdx.x*256 + threadIdx.x;
  int x = idx & 127, y = (idx>>7) & 127, bb = idx >> 14;
  const float* bp = bsrc + (size_t)bb*C_IN*H*W;
  float a1[IC], a2[IC];
  #pragma unroll
  for (int o=0;o<IC;o++){ a1[o]=s_bg[o]; a2[o]=s_bt[o]; }
  for (int c=0;c<C_IN;c++){
    const float* bc = bp + c*H*W;
    float ctr = bc[y*W+x];
    #pragma unroll
    for (int o=0;o<IC;o++) a2[o] += ctr * s_wt[o*C_IN + c];
    #pragma unroll
    for (int dy=0; dy<3; dy++){
      int yy = y + dy - 1;
      if ((unsigned)yy >= (unsigned)H) continue;
      #pragma unroll
      for (int dx=0; dx<3; dx++){
        int xx = x + dx - 1;
        if ((unsigned)xx >= (unsigned)W) continue;
        float v = bc[yy*W+xx];
        #pragma unroll
        for (int o=0;o<IC;o++) a1[o] += v * s_wg[(o*C_IN + c)*9 + dy*3 + dx];
      }
    }
  }
  #pragma unroll
  for (int o=0;o<IC;o++){
    b1[((size_t)(bb*IC+o)*H + y)*W + x] = a1[o];
    b2[((size_t)(bb*IC+o)*H + y)*W + x] = a2[o];
  }
}

// ---------------- K1b: 4 x-shifted zero-padded bf16 copies of b2 ------------
__global__ __launch_bounds__(256) void k_prep(
    const float* __restrict__ b2, unsigned short* __restrict__ b2p) {
  int i = blockIdx.x*256 + threadIdx.x;
  if (i >= 2*B2P_PER_B) return;
  int bb = i / B2P_PER_B;
  int r = i % B2P_PER_B;
  int s = r / (5*136*136);
  int r2 = r % (5*136*136);
  int c = r2 / (136*136);
  int r3 = r2 % (136*136);
  int ry = r3 / 136, u = r3 % 136;
  int gy = ry - 3, gx = u + s - 3;
  float v = 0.f;
  if (c < 4 && (unsigned)gy < (unsigned)H && (unsigned)gx < (unsigned)W)
    v = b2[((size_t)(bb*IC + c)*H + gy)*W + gx];
  b2p[i] = f2bf(v);
}

// ---------------- K2: xiT[q][128] = bf16 hi/lo of relu(7x7x4 conv), + meanxi
__global__ __launch_bounds__(128) void k_xi(
    const float* __restrict__ b1, const float* __restrict__ w_fc2, const float* __restrict__ b_fc2,
    unsigned short* __restrict__ xiT, float* __restrict__ meanxi) {
  __shared__ float s_w[G*F];
  __shared__ float s_b[G];
  __shared__ float s_p[IC*7*136];
  __shared__ float s_red[2][G];
  int tid = threadIdx.x;
  for (int i=tid;i<G*F;i+=128) s_w[i] = w_fc2[i];
  if (tid < G) s_b[tid] = b_fc2[tid];
  int bb = blockIdx.x >> 7, y = blockIdx.x & 127;
  for (int i=tid; i<IC*7*136; i+=128) {
    int col = i % 136; int t = i / 136; int ki = t % 7; int c = t / 7;
    int gy = y - 3 + ki, gx = col - 3;
    float v = 0.f;
    if ((unsigned)gy < (unsigned)H && (unsigned)gx < (unsigned)W && col < 134)
      v = b1[((size_t)(bb*IC+c)*H + gy)*W + gx];
    s_p[i] = v;
  }
  __syncthreads();
  int x = tid;
  float acc[G];
  #pragma unroll
  for (int g=0; g<G; g++) acc[g] = s_b[g];
  for (int c=0;c<IC;c++)
    for (int ki=0;ki<7;ki++){
      const float* prow = &s_p[(c*7+ki)*136 + x];
      #pragma unroll
      for (int kj=0;kj<7;kj++){
        float pv = prow[kj];
        int f = c*49 + ki*7 + kj;
        #pragma unroll
        for (int g=0; g<G; g++) acc[g] += pv * s_w[g*F + f];
      }
    }
  #pragma unroll
  for (int g=0; g<G; g++) acc[g] = fmaxf(acc[g], 0.f);
  for (int g=0; g<G; ++g){
    float v = acc[g];
    #pragma unroll
    for (int off=1; off<64; off<<=1) v += __shfl_xor(v, off);
    if ((tid&63)==0) s_red[tid>>6][g] = v;
  }
  __syncthreads();
  if (tid < G) atomicAdd(&meanxi[bb*G + tid], (s_red[0][tid]+s_red[1][tid]) * (1.f/(float)Q));
  // xiT row: [0..63]=hi bf16 (k<49 else 0), [64..127]=lo residual bf16
  unsigned short* xr = xiT + ((size_t)((bb<<14) + y*W + x))*128;
  #pragma unroll
  for (int c=0; c<16; ++c){
    unsigned u[4];
    #pragma unroll
    for (int jj=0; jj<4; ++jj){
      int e0 = c*8 + jj*2, e1 = e0+1;
      if (c < 8){
        float v0 = (e0<G)?acc[e0]:0.f, v1 = (e1<G)?acc[e1]:0.f;
        u[jj] = (unsigned)f2bf(v0) | (((unsigned)f2bf(v1))<<16);
      } else {
        int k0 = e0-64, k1 = e1-64;
        float w0 = (k0<G)?acc[k0]:0.f; unsigned short h0 = f2bf(w0); float l0 = w0 - bf2f(h0);
        float w1 = (k1<G)?acc[k1]:0.f; unsigned short h1 = f2bf(w1); float l1 = w1 - bf2f(h1);
        u[jj] = (unsigned)f2bf(l0) | (((unsigned)f2bf(l1))<<16);
      }
    }
    uint4 q4 = {u[0],u[1],u[2],u[3]};
    *(uint4*)&xr[c*8] = q4;
  }
}

// ---------------- K4: wiP[p][128] = bf16 hi/lo of relu(7x7 s4 conv) ---------
__global__ __launch_bounds__(256) void k_wi(
    const float* __restrict__ b1, const float* __restrict__ w_fc1, const float* __restrict__ b_fc1,
    unsigned short* __restrict__ wiP) {
  int i = blockIdx.x*256 + threadIdx.x;
  if (i >= 2*L*64) return;
  int g = i & 63; int p = (i >> 6) & 1023; int bb = i >> 16;
  float acc = 0.f;
  if (g < G){
    acc = b_fc1[g];
    int py = p >> 5, px = p & 31;
    const float* wrow = w_fc1 + (size_t)g*F;
    for (int c=0;c<IC;c++){
      const float* bc = b1 + (size_t)(bb*IC+c)*H*W;
      for (int ki=0;ki<7;ki++){
        int yy = py*4 - 1 + ki;
        if ((unsigned)yy >= (unsigned)H) continue;
        #pragma unroll
        for (int kj=0;kj<7;kj++){
          int xx = px*4 - 1 + kj;
          if ((unsigned)xx >= (unsigned)W) continue;
          acc += bc[yy*W+xx] * wrow[c*49 + ki*7 + kj];
        }
      }
    }
    acc = fmaxf(acc, 0.f);
  }
  unsigned short h = f2bf(acc);
  float l = acc - bf2f(h);
  size_t base = ((size_t)((bb<<10)+p))*128;
  wiP[base + g] = h;
  wiP[base + 64 + g] = f2bf(l);
}

// ---------------- K5: thr[b,p], bias[b,p] -----------------------------------
__global__ __launch_bounds__(256) void k_thrbias(
    const float* __restrict__ bsrc, const float* __restrict__ w_thr, const float* __restrict__ b_thr,
    const float* __restrict__ w_bias, const float* __restrict__ b_bias,
    float* __restrict__ thr, float* __restrict__ bias) {
  int tid = threadIdx.x;
  int c = tid & 31, pl = tid >> 5;
  int pg = blockIdx.x*8 + pl;
  int bb = pg >> 10, p = pg & 1023;
  int py = p >> 5, px = p & 31;
  const float* bc = bsrc + (size_t)(bb*C_IN + c)*H*W;
  float ta = 0.f, ba = 0.f;
  for (int ki=0;ki<7;ki++){
    int yy = py*4 - 1 + ki;
    if ((unsigned)yy >= (unsigned)H) continue;
    #pragma unroll
    for (int kj=0;kj<7;kj++){
      int xx = px*4 - 1 + kj;
      if ((unsigned)xx >= (unsigned)W) continue;
      float v = bc[yy*W+xx];
      ta += v * w_thr[c*49 + ki*7 + kj];
      ba += v * w_bias[c*49 + ki*7 + kj];
    }
  }
  #pragma unroll
  for (int off=1; off<32; off<<=1){ ta += __shfl_xor(ta, off); ba += __shfl_xor(ba, off); }
  if (c == 0) { thr[pg] = ta + b_thr[0]; bias[pg] = ba + b_bias[0]; }
}

// ---------------- K6: rowmean[b,p] = wi . meanxi ----------------------------
__global__ __launch_bounds__(256) void k_rowmean(
    const unsigned short* __restrict__ wiP, const float* __restrict__ meanxi, float* __restrict__ rowmean){
  int i = blockIdx.x*256 + threadIdx.x;
  if (i >= 2*L) return;
  int bb = i >> 10;
  const unsigned short* wr = wiP + (size_t)i*128;
  const float* mx = meanxi + bb*G;
  float s = 0.f;
  #pragma unroll
  for (int g=0; g<G; g++) s += (bf2f(wr[g]) + bf2f(wr[64+g])) * mx[g];
  rowmean[i] = s;
}

// ---------------- K7: fused attention, MFMA scores + MFMA PV ----------------
// grid = 2 bb x 32 ptile(32 rows) x 8 q-splits(2048 q, 2 online tiles of 1024)
// 512 thr (8 waves). Each wave owns a 128-q slice of the current 1024-q tile.
__global__ __launch_bounds__(512, 4) void k_attn(
    const unsigned short* __restrict__ b2p, const unsigned short* __restrict__ xiT,
    const unsigned short* __restrict__ wiP, const float* __restrict__ thr,
    const float* __restrict__ bias, const float* __restrict__ rowmean,
    __half* __restrict__ pacc, float* __restrict__ pm, float* __restrict__ pd) {
  __shared__ unsigned short sW[32*1032];
  __shared__ float sMaxW[8][32], sSumW[8][32];
  __shared__ float sAlpha[32];
  int tid = threadIdx.x, lane = tid & 63, wave = tid >> 6;
  int l16 = lane & 15, lg = lane >> 4;
  int wid = blockIdx.x;
  int sp = wid & 7, pt = (wid >> 3) & 31, bb = wid >> 8;
  // per-hf coef
  float cf[2];
  #pragma unroll
  for (int hf=0; hf<2; ++hf){
    int gi = (bb<<10) + pt*32 + hf*16 + l16;
    cf[hf] = bias[gi] - rowmean[gi]*thr[gi];
  }
  // phase-B f-columns
  int t0 = wave, t1c = (wave + 8 > 12) ? 12 : wave + 8;
  int ok1 = (wave + 8 < 13);
  int f0 = t0*16 + l16;
  int fc0 = f0/49, r0 = f0%49, ki0 = r0/7, kj0 = r0%7;
  int At0 = (((kj0&3)*5 + fc0)*136 + ki0)*136 + (kj0&4);
  int f1 = t1c*16 + l16;
  int fc1 = f1/49, r1 = f1%49, ki1 = r1/7, kj1 = r1%7;
  int At1 = (((kj1&3)*5 + fc1)*136 + ki1)*136 + (kj1&4);
  int bbase = bb * B2P_PER_B;

  float m_run[2] = {0.f, 0.f}, d_run[2] = {0.f, 0.f}, al[2];
  floatx4 acc00 = {0,0,0,0}, acc01 = {0,0,0,0}, acc10 = {0,0,0,0}, acc11 = {0,0,0,0};

  for (int t=0; t<2; ++t){
    int q0 = sp*2048 + t*1024;
    const unsigned short* xibase = xiT + ((size_t)((bb<<14) + q0 + wave*128))*128;
    // ---------- phase A: split-bf16 MFMA scores + softmax tile ----------
    #pragma unroll
    for (int hf=0; hf<2; ++hf){
      int prow = hf*16 + l16;
      const unsigned short* wrow = wiP + (size_t)((bb<<10) + pt*32 + prow)*128;
      uint4 bh0 = *(const uint4*)&wrow[lg*8];
      uint4 bh1 = *(const uint4*)&wrow[32 + lg*8];
      uint4 bl0 = *(const uint4*)&wrow[64 + lg*8];
      uint4 bl1 = *(const uint4*)&wrow[96 + lg*8];
      float st[8][4];
      unsigned mball = 0u;
      float mx = 0.f;
      #pragma unroll
      for (int Mt=0; Mt<8; ++Mt){
        const unsigned short* xr = xibase + (size_t)(Mt*16 + l16)*128;
        uint4 ah0 = *(const uint4*)&xr[lg*8];
        uint4 ah1 = *(const uint4*)&xr[32 + lg*8];
        uint4 al0 = *(const uint4*)&xr[64 + lg*8];
        uint4 al1 = *(const uint4*)&xr[96 + lg*8];
        floatx4 a = {0.f,0.f,0.f,0.f};
        a = mfma16(ah0, bh0, a);
        a = mfma16(ah1, bh1, a);
        a = mfma16(ah0, bl0, a);
        a = mfma16(ah1, bl1, a);
        a = mfma16(al0, bh0, a);
        a = mfma16(al1, bh1, a);
        #pragma unroll
        for (int j=0;j<4;j++){
          float s = a[j];
          float xm = s + cf[hf];
          if (xm > 0.f) mball |= (1u << (Mt*4 + j));
          float v = s * fmaxf(xm, 0.f) * SCALE;
          st[Mt][j] = v;
          mx = fmaxf(mx, v);
        }
      }
      mx = fmaxf(mx, __shfl_xor(mx, 16));
      mx = fmaxf(mx, __shfl_xor(mx, 32));
      if (lg == 0) sMaxW[wave][prow] = mx;
      __syncthreads();
      float mn = m_run[hf];
      #pragma unroll
      for (int w=0; w<8; ++w) mn = fmaxf(mn, sMaxW[w][prow]);
      al[hf] = __expf(m_run[hf] - mn);
      m_run[hf] = mn;
      if (wave == 0 && lg == 0) sAlpha[prow] = al[hf];
      float sum = 0.f;
      #pragma unroll
      for (int Mt=0; Mt<8; ++Mt){
        float e0 = __expf(st[Mt][0]-mn), e1 = __expf(st[Mt][1]-mn);
        float e2 = __expf(st[Mt][2]-mn), e3 = __expf(st[Mt][3]-mn);
        sum += e0+e1+e2+e3;
        unsigned mb = mball >> (Mt*4);
        unsigned w0 = ((mb&1u)? (unsigned)f2bf(e0):0u) | (((mb&2u)? (unsigned)f2bf(e1):0u)<<16);
        unsigned w1 = ((mb&4u)? (unsigned)f2bf(e2):0u) | (((mb&8u)? (unsigned)f2bf(e3):0u)<<16);
        uint2 pv = {w0, w1};
        *(uint2*)&sW[prow*1032 + wave*128 + Mt*16 + lg*4] = pv;
      }
      sum += __shfl_xor(sum, 16);
      sum += __shfl_xor(sum, 32);
      if (lg == 0) sSumW[wave][prow] = sum;
    }
    __syncthreads();
    // ---------- d update + phase B: PV MFMA with rescale ----------
    #pragma unroll
    for (int hf=0; hf<2; ++hf){
      float ts = 0.f;
      #pragma unroll
      for (int w=0; w<8; ++w) ts += sSumW[w][hf*16 + l16];
      d_run[hf] = d_run[hf]*al[hf] + ts;
    }
    floatx4 av0 = { sAlpha[lg*4+0], sAlpha[lg*4+1], sAlpha[lg*4+2], sAlpha[lg*4+3] };
    floatx4 av1 = { sAlpha[16+lg*4+0], sAlpha[16+lg*4+1], sAlpha[16+lg*4+2], sAlpha[16+lg*4+3] };
    acc00 *= av0; acc10 *= av0; acc01 *= av1; acc11 *= av1;
    int ybase = q0 >> 7;
    for (int ks=0; ks<32; ++ks){
      int kk = ks*32 + lg*8;
      int y = ybase + (kk >> 7), x8 = kk & 127;
      int gb = bbase + y*136 + x8;
      uint4 a0 = *(const uint4*)&sW[l16*1032 + kk];
      uint4 a1 = *(const uint4*)&sW[(16+l16)*1032 + kk];
      const unsigned short* p0 = b2p + gb + At0;
      uint2 b0lo = *(const uint2*)p0;
      uint2 b0hi = *(const uint2*)(p0 + 4);
      uint4 b0 = {b0lo.x, b0lo.y, b0hi.x, b0hi.y};
      const unsigned short* p1 = b2p + gb + At1;
      uint2 b1lo = *(const uint2*)p1;
      uint2 b1hi = *(const uint2*)(p1 + 4);
      uint4 b1v = {b1lo.x, b1lo.y, b1hi.x, b1hi.y};
      acc00 = mfma16(a0, b0, acc00);
      acc01 = mfma16(a1, b0, acc01);
      acc10 = mfma16(a0, b1v, acc10);
      acc11 = mfma16(a1, b1v, acc11);
    }
  }
  int pbase = ((bb*32 + pt)*8 + sp)*32;
  #pragma unroll
  for (int j=0;j<4;j++){
    int row0 = pbase + lg*4 + j;
    int row1 = pbase + 16 + lg*4 + j;
    if (f0 < F){
      pacc[(size_t)row0*F + f0] = __float2half(acc00[j]);
      pacc[(size_t)row1*F + f0] = __float2half(acc01[j]);
    }
    if (ok1 && f1 < F){
      pacc[(size_t)row0*F + f1] = __float2half(acc10[j]);
      pacc[(size_t)row1*F + f1] = __float2half(acc11[j]);
    }
  }
  if (wave == 0 && lg == 0){
    #pragma unroll
    for (int hf=0; hf<2; ++hf){
      int prow = hf*16 + l16;
      pm[pbase + prow] = m_run[hf];
      pd[pbase + prow] = d_run[hf];
    }
  }
}

// ---------------- K8: combine the 8 q-splits --------------------------------
__global__ __launch_bounds__(256) void k_combine(
    const __half* __restrict__ pacc, const float* __restrict__ pm, const float* __restrict__ pd,
    float* __restrict__ outpf){
  int i = blockIdx.x*256 + threadIdx.x;
  if (i >= 2*L*F) return;
  int f = i % F; int p = (i/F) % L; int bb = i/(F*L);
  int pt = p >> 5, r = p & 31;
  int base = ((bb*32 + pt)*8)*32 + r;
  float M = 0.f;
  #pragma unroll
  for (int hh=0; hh<NH; hh++) M = fmaxf(M, pm[base + hh*32]);
  float num = 0.f, den = 0.f;
  #pragma unroll
  for (int hh=0; hh<NH; hh++){
    float e = __expf(pm[base + hh*32] - M);
    num += e * __half2float(pacc[(size_t)(base + hh*32)*F + f]);
    den += e * pd[base + hh*32];
  }
  outpf[(size_t)(bb*L + p)*F + f] = num/den;
}

// ---------------- K9: fold + count-normalize --------------------------------
__global__ __launch_bounds__(256) void k_fold(const float* __restrict__ outpf, float* __restrict__ out){
  int i = blockIdx.x*256 + threadIdx.x;
  if (i >= 2*IC*H*W) return;
  int ww = i & 127, hh = (i>>7)&127, c = (i>>14)&3, bb = i>>16;
  int H3 = hh+3, W3 = ww+3;
  int py0 = (H3-3)>>2, py1 = min(31, H3>>2);
  int px0 = (W3-3)>>2, px1 = min(31, W3>>2);
  float s = 0.f; int cnt = 0;
  for (int py=py0; py<=py1; py++){
    int ki = H3 - 4*py;
    for (int px=px0; px<=px1; px++){
      int kj = W3 - 4*px;
      s += outpf[(size_t)((bb<<10) + py*32 + px)*F + c*49 + ki*7 + kj];
      cnt++;
    }
  }
  out[i] = s / (float)cnt;
}

extern "C" void kernel_launch(void* const* d_in, const int* in_sizes, int n_in,
                              void* d_out, int out_size, void* d_ws, size_t ws_size,
                              hipStream_t stream) {
  const float* b      = (const float*)d_in[0];
  const float* w_g    = (const float*)d_in[1];
  const float* b_g    = (const float*)d_in[2];
  const float* w_t    = (const float*)d_in[3];
  const float* b_t    = (const float*)d_in[4];
  const float* w_fc1  = (const float*)d_in[5];
  const float* b_fc1  = (const float*)d_in[6];
  const float* w_fc2  = (const float*)d_in[7];
  const float* b_fc2  = (const float*)d_in[8];
  const float* w_thr  = (const float*)d_in[9];
  const float* b_thr  = (const float*)d_in[10];
  const float* w_bias = (const float*)d_in[11];
  const float* b_bias = (const float*)d_in[12];
  float* out = (float*)d_out;
  float* ws = (float*)d_ws;

  // workspace layout (float-word offsets), total 4,504,960 words = 18.0 MB
  float* b1      = ws;                                    // 131072
  float* b2      = b1 + 131072;                           // 131072
  unsigned short* xiT = (unsigned short*)(ws + 262144);   // 4,194,304 u16 = 2,097,152 w
  unsigned short* wiP = (unsigned short*)(ws + 2359296);  // 262,144 u16 = 131,072 w
  float* meanxi  = ws + 2490368;                          // 128
  float* thr     = ws + 2490496;                          // 2048
  float* bias    = ws + 2492544;                          // 2048
  float* rowmean = ws + 2494592;                          // 2048
  unsigned short* b2p = (unsigned short*)(ws + 2496640);  // 739,840 u16 = 369,920 w
  __half* pacc   = (__half*)(ws + 2866560);               // 3,211,264 half = 1,605,632 w
  float* pm      = ws + 4472192;                          // 16384
  float* pd      = ws + 4488576;                          // 16384
  float* outpf   = ws + 262144;                           // alias xiT (dead after k_attn)
  (void)in_sizes; (void)n_in; (void)out_size; (void)ws_size;

  hipMemsetAsync(meanxi, 0, 2*G*sizeof(float), stream);
  k_front  <<<128, 256, 0, stream>>>(b, w_g, b_g, w_t, b_t, b1, b2);
  k_prep   <<<(2*B2P_PER_B + 255)/256, 256, 0, stream>>>(b2, b2p);
  k_xi     <<<256, 128, 0, stream>>>(b1, w_fc2, b_fc2, xiT, meanxi);
  k_wi     <<<(2*L*64 + 255)/256, 256, 0, stream>>>(b1, w_fc1, b_fc1, wiP);
  k_thrbias<<<256, 256, 0, stream>>>(b, w_thr, b_thr, w_bias, b_bias, thr, bias);
  k_rowmean<<<8,   256, 0, stream>>>(wiP, meanxi, rowmean);
  k_attn   <<<512, 512, 0, stream>>>(b2p, xiT, wiP, thr, bias, rowmean, pacc, pm, pd);
  k_combine<<<(2*L*F + 255)/256, 256, 0, stream>>>(pacc, pm, pd, outpf);
  k_fold   <<<512, 256, 0, stream>>>(outpf, out);
}

// Round 5
// 377.691 us; speedup vs baseline: 2.4412x; 1.0755x over previous
//
#include <hip/hip_runtime.h>
#include <hip/hip_fp16.h>
#include <math.h>

static constexpr int C_IN = 32, IC = 4, H = 128, W = 128, G = 49, F = 196;
static constexpr int L = 1024, Q = 16384;
static constexpr float SCALE = 10.f;
static constexpr int NH = 8;       // q-splits (2048 q each, 2 online tiles of 1024)
static constexpr int B2P_PER_B = 4*5*136*136;  // 369920 bf16 elems per batch

typedef __attribute__((ext_vector_type(8))) short short8;
typedef __attribute__((ext_vector_type(4))) float floatx4;

__device__ __forceinline__ unsigned short f2bf(float f){
  unsigned u = __float_as_uint(f);
  return (unsigned short)((u + 0x7fffu + ((u >> 16) & 1u)) >> 16);
}
__device__ __forceinline__ float bf2f(unsigned short h){
  return __uint_as_float(((unsigned)h) << 16);
}
__device__ __forceinline__ floatx4 mfma16(uint4 a, uint4 b, floatx4 c){
  return __builtin_amdgcn_mfma_f32_16x16x32_bf16(*(short8*)&a, *(short8*)&b, c, 0, 0, 0);
}

// ---------------- K1: b1 = 3x3 conv (32->4, pad1), b2 = 1x1 conv (32->4) ----
__global__ __launch_bounds__(256) void k_front(
    const float* __restrict__ bsrc, const float* __restrict__ w_g, const float* __restrict__ b_g,
    const float* __restrict__ w_t, const float* __restrict__ b_t,
    float* __restrict__ b1, float* __restrict__ b2) {
  __shared__ float s_wg[IC*C_IN*9];
  __shared__ float s_wt[IC*C_IN];
  __shared__ float s_bg[IC], s_bt[IC];
  for (int i = threadIdx.x; i < IC*C_IN*9; i += 256) s_wg[i] = w_g[i];
  for (int i = threadIdx.x; i < IC*C_IN; i += 256) s_wt[i] = w_t[i];
  if (threadIdx.x < IC) { s_bg[threadIdx.x] = b_g[threadIdx.x]; s_bt[threadIdx.x] = b_t[threadIdx.x]; }
  __syncthreads();
  int idx = blockIdx.x*256 + threadIdx.x;
  int x = idx & 127, y = (idx>>7) & 127, bb = idx >> 14;
  const float* bp = bsrc + (size_t)bb*C_IN*H*W;
  float a1[IC], a2[IC];
  #pragma unroll
  for (int o=0;o<IC;o++){ a1[o]=s_bg[o]; a2[o]=s_bt[o]; }
  for (int c=0;c<C_IN;c++){
    const float* bc = bp + c*H*W;
    float ctr = bc[y*W+x];
    #pragma unroll
    for (int o=0;o<IC;o++) a2[o] += ctr * s_wt[o*C_IN + c];
    #pragma unroll
    for (int dy=0; dy<3; dy++){
      int yy = y + dy - 1;
      if ((unsigned)yy >= (unsigned)H) continue;
      #pragma unroll
      for (int dx=0; dx<3; dx++){
        int xx = x + dx - 1;
        if ((unsigned)xx >= (unsigned)W) continue;
        float v = bc[yy*W+xx];
        #pragma unroll
        for (int o=0;o<IC;o++) a1[o] += v * s_wg[(o*C_IN + c)*9 + dy*3 + dx];
      }
    }
  }
  #pragma unroll
  for (int o=0;o<IC;o++){
    b1[((size_t)(bb*IC+o)*H + y)*W + x] = a1[o];
    b2[((size_t)(bb*IC+o)*H + y)*W + x] = a2[o];
  }
}

// ---------------- K1b: 4 x-shifted zero-padded bf16 copies of b2 ------------
__global__ __launch_bounds__(256) void k_prep(
    const float* __restrict__ b2, unsigned short* __restrict__ b2p) {
  int i = blockIdx.x*256 + threadIdx.x;
  if (i >= 2*B2P_PER_B) return;
  int bb = i / B2P_PER_B;
  int r = i % B2P_PER_B;
  int s = r / (5*136*136);
  int r2 = r % (5*136*136);
  int c = r2 / (136*136);
  int r3 = r2 % (136*136);
  int ry = r3 / 136, u = r3 % 136;
  int gy = ry - 3, gx = u + s - 3;
  float v = 0.f;
  if (c < 4 && (unsigned)gy < (unsigned)H && (unsigned)gx < (unsigned)W)
    v = b2[((size_t)(bb*IC + c)*H + gy)*W + gx];
  b2p[i] = f2bf(v);
}

// ---------------- K2: xiT[q][128] = bf16 hi/lo of relu(7x7x4 conv), + meanxi
__global__ __launch_bounds__(128) void k_xi(
    const float* __restrict__ b1, const float* __restrict__ w_fc2, const float* __restrict__ b_fc2,
    unsigned short* __restrict__ xiT, float* __restrict__ meanxi) {
  __shared__ float s_w[G*F];
  __shared__ float s_b[G];
  __shared__ float s_p[IC*7*136];
  __shared__ float s_red[2][G];
  int tid = threadIdx.x;
  for (int i=tid;i<G*F;i+=128) s_w[i] = w_fc2[i];
  if (tid < G) s_b[tid] = b_fc2[tid];
  int bb = blockIdx.x >> 7, y = blockIdx.x & 127;
  for (int i=tid; i<IC*7*136; i+=128) {
    int col = i % 136; int t = i / 136; int ki = t % 7; int c = t / 7;
    int gy = y - 3 + ki, gx = col - 3;
    float v = 0.f;
    if ((unsigned)gy < (unsigned)H && (unsigned)gx < (unsigned)W && col < 134)
      v = b1[((size_t)(bb*IC+c)*H + gy)*W + gx];
    s_p[i] = v;
  }
  __syncthreads();
  int x = tid;
  float acc[G];
  #pragma unroll
  for (int g=0; g<G; g++) acc[g] = s_b[g];
  for (int c=0;c<IC;c++)
    for (int ki=0;ki<7;ki++){
      const float* prow = &s_p[(c*7+ki)*136 + x];
      #pragma unroll
      for (int kj=0;kj<7;kj++){
        float pv = prow[kj];
        int f = c*49 + ki*7 + kj;
        #pragma unroll
        for (int g=0; g<G; g++) acc[g] += pv * s_w[g*F + f];
      }
    }
  #pragma unroll
  for (int g=0; g<G; g++) acc[g] = fmaxf(acc[g], 0.f);
  for (int g=0; g<G; ++g){
    float v = acc[g];
    #pragma unroll
    for (int off=1; off<64; off<<=1) v += __shfl_xor(v, off);
    if ((tid&63)==0) s_red[tid>>6][g] = v;
  }
  __syncthreads();
  if (tid < G) atomicAdd(&meanxi[bb*G + tid], (s_red[0][tid]+s_red[1][tid]) * (1.f/(float)Q));
  // xiT row: [0..63]=hi bf16 (k<49 else 0), [64..127]=lo residual bf16
  unsigned short* xr = xiT + ((size_t)((bb<<14) + y*W + x))*128;
  #pragma unroll
  for (int c=0; c<16; ++c){
    unsigned u[4];
    #pragma unroll
    for (int jj=0; jj<4; ++jj){
      int e0 = c*8 + jj*2, e1 = e0+1;
      if (c < 8){
        float v0 = (e0<G)?acc[e0]:0.f, v1 = (e1<G)?acc[e1]:0.f;
        u[jj] = (unsigned)f2bf(v0) | (((unsigned)f2bf(v1))<<16);
      } else {
        int k0 = e0-64, k1 = e1-64;
        float w0 = (k0<G)?acc[k0]:0.f; unsigned short h0 = f2bf(w0); float l0 = w0 - bf2f(h0);
        float w1 = (k1<G)?acc[k1]:0.f; unsigned short h1 = f2bf(w1); float l1 = w1 - bf2f(h1);
        u[jj] = (unsigned)f2bf(l0) | (((unsigned)f2bf(l1))<<16);
      }
    }
    uint4 q4 = {u[0],u[1],u[2],u[3]};
    *(uint4*)&xr[c*8] = q4;
  }
}

// ---------------- K4: wiP[p][128] = bf16 hi/lo of relu(7x7 s4 conv) ---------
__global__ __launch_bounds__(256) void k_wi(
    const float* __restrict__ b1, const float* __restrict__ w_fc1, const float* __restrict__ b_fc1,
    unsigned short* __restrict__ wiP) {
  int i = blockIdx.x*256 + threadIdx.x;
  if (i >= 2*L*64) return;
  int g = i & 63; int p = (i >> 6) & 1023; int bb = i >> 16;
  float acc = 0.f;
  if (g < G){
    acc = b_fc1[g];
    int py = p >> 5, px = p & 31;
    const float* wrow = w_fc1 + (size_t)g*F;
    for (int c=0;c<IC;c++){
      const float* bc = b1 + (size_t)(bb*IC+c)*H*W;
      for (int ki=0;ki<7;ki++){
        int yy = py*4 - 1 + ki;
        if ((unsigned)yy >= (unsigned)H) continue;
        #pragma unroll
        for (int kj=0;kj<7;kj++){
          int xx = px*4 - 1 + kj;
          if ((unsigned)xx >= (unsigned)W) continue;
          acc += bc[yy*W+xx] * wrow[c*49 + ki*7 + kj];
        }
      }
    }
    acc = fmaxf(acc, 0.f);
  }
  unsigned short h = f2bf(acc);
  float l = acc - bf2f(h);
  size_t base = ((size_t)((bb<<10)+p))*128;
  wiP[base + g] = h;
  wiP[base + 64 + g] = f2bf(l);
}

// ---------------- K5: thr[b,p], bias[b,p] -----------------------------------
__global__ __launch_bounds__(256) void k_thrbias(
    const float* __restrict__ bsrc, const float* __restrict__ w_thr, const float* __restrict__ b_thr,
    const float* __restrict__ w_bias, const float* __restrict__ b_bias,
    float* __restrict__ thr, float* __restrict__ bias) {
  int tid = threadIdx.x;
  int c = tid & 31, pl = tid >> 5;
  int pg = blockIdx.x*8 + pl;
  int bb = pg >> 10, p = pg & 1023;
  int py = p >> 5, px = p & 31;
  const float* bc = bsrc + (size_t)(bb*C_IN + c)*H*W;
  float ta = 0.f, ba = 0.f;
  for (int ki=0;ki<7;ki++){
    int yy = py*4 - 1 + ki;
    if ((unsigned)yy >= (unsigned)H) continue;
    #pragma unroll
    for (int kj=0;kj<7;kj++){
      int xx = px*4 - 1 + kj;
      if ((unsigned)xx >= (unsigned)W) continue;
      float v = bc[yy*W+xx];
      ta += v * w_thr[c*49 + ki*7 + kj];
      ba += v * w_bias[c*49 + ki*7 + kj];
    }
  }
  #pragma unroll
  for (int off=1; off<32; off<<=1){ ta += __shfl_xor(ta, off); ba += __shfl_xor(ba, off); }
  if (c == 0) { thr[pg] = ta + b_thr[0]; bias[pg] = ba + b_bias[0]; }
}

// ---------------- K6: rowmean[b,p] = wi . meanxi ----------------------------
__global__ __launch_bounds__(256) void k_rowmean(
    const unsigned short* __restrict__ wiP, const float* __restrict__ meanxi, float* __restrict__ rowmean){
  int i = blockIdx.x*256 + threadIdx.x;
  if (i >= 2*L) return;
  int bb = i >> 10;
  const unsigned short* wr = wiP + (size_t)i*128;
  const float* mx = meanxi + bb*G;
  float s = 0.f;
  #pragma unroll
  for (int g=0; g<G; g++) s += (bf2f(wr[g]) + bf2f(wr[64+g])) * mx[g];
  rowmean[i] = s;
}

// ---------------- K7: fused attention, MFMA scores + MFMA PV ----------------
// grid = 2 bb x 32 ptile(32 rows) x 8 q-splits(2048 q, 2 online tiles of 1024)
// 512 thr (8 waves). Each wave owns a 128-q slice of the current 1024-q tile.
// launch_bounds (512,2): cap 256 unified VGPR -> no scratch spill (R4 lesson).
__global__ __launch_bounds__(512, 2) void k_attn(
    const unsigned short* __restrict__ b2p, const unsigned short* __restrict__ xiT,
    const unsigned short* __restrict__ wiP, const float* __restrict__ thr,
    const float* __restrict__ bias, const float* __restrict__ rowmean,
    __half* __restrict__ pacc, float* __restrict__ pm, float* __restrict__ pd) {
  __shared__ unsigned short sW[32*1032];
  __shared__ float sMaxW[8][32], sSumW[8][32];
  __shared__ float sAlpha[32];
  int tid = threadIdx.x, lane = tid & 63, wave = tid >> 6;
  int l16 = lane & 15, lg = lane >> 4;
  int wid = blockIdx.x;
  int sp = wid & 7, pt = (wid >> 3) & 31, bb = wid >> 8;
  // per-hf coef
  float cf[2];
  #pragma unroll
  for (int hf=0; hf<2; ++hf){
    int gi = (bb<<10) + pt*32 + hf*16 + l16;
    cf[hf] = bias[gi] - rowmean[gi]*thr[gi];
  }
  // phase-B f-columns
  int t0 = wave, t1c = (wave + 8 > 12) ? 12 : wave + 8;
  int ok1 = (wave + 8 < 13);
  int f0 = t0*16 + l16;
  int fc0 = f0/49, r0 = f0%49, ki0 = r0/7, kj0 = r0%7;
  int At0 = (((kj0&3)*5 + fc0)*136 + ki0)*136 + (kj0&4);
  int f1 = t1c*16 + l16;
  int fc1 = f1/49, r1 = f1%49, ki1 = r1/7, kj1 = r1%7;
  int At1 = (((kj1&3)*5 + fc1)*136 + ki1)*136 + (kj1&4);
  int bbase = bb * B2P_PER_B;

  float m_run[2] = {0.f, 0.f}, d_run[2] = {0.f, 0.f}, al[2];
  floatx4 acc00 = {0,0,0,0}, acc01 = {0,0,0,0}, acc10 = {0,0,0,0}, acc11 = {0,0,0,0};

  for (int t=0; t<2; ++t){
    int q0 = sp*2048 + t*1024;
    const unsigned short* xibase = xiT + ((size_t)((bb<<14) + q0 + wave*128))*128;
    // ---------- phase A: split-bf16 MFMA scores + softmax tile ----------
    #pragma unroll
    for (int hf=0; hf<2; ++hf){
      int prow = hf*16 + l16;
      const unsigned short* wrow = wiP + (size_t)((bb<<10) + pt*32 + prow)*128;
      uint4 bh0 = *(const uint4*)&wrow[lg*8];
      uint4 bh1 = *(const uint4*)&wrow[32 + lg*8];
      uint4 bl0 = *(const uint4*)&wrow[64 + lg*8];
      uint4 bl1 = *(const uint4*)&wrow[96 + lg*8];
      float st[8][4];
      unsigned mball = 0u;
      float mx = 0.f;
      #pragma unroll
      for (int Mt=0; Mt<8; ++Mt){
        const unsigned short* xr = xibase + (size_t)(Mt*16 + l16)*128;
        uint4 ah0 = *(const uint4*)&xr[lg*8];
        uint4 ah1 = *(const uint4*)&xr[32 + lg*8];
        uint4 al0 = *(const uint4*)&xr[64 + lg*8];
        uint4 al1 = *(const uint4*)&xr[96 + lg*8];
        floatx4 a = {0.f,0.f,0.f,0.f};
        a = mfma16(ah0, bh0, a);
        a = mfma16(ah1, bh1, a);
        a = mfma16(ah0, bl0, a);
        a = mfma16(ah1, bl1, a);
        a = mfma16(al0, bh0, a);
        a = mfma16(al1, bh1, a);
        #pragma unroll
        for (int j=0;j<4;j++){
          float s = a[j];
          float xm = s + cf[hf];
          if (xm > 0.f) mball |= (1u << (Mt*4 + j));
          float v = s * fmaxf(xm, 0.f) * SCALE;
          st[Mt][j] = v;
          mx = fmaxf(mx, v);
        }
      }
      mx = fmaxf(mx, __shfl_xor(mx, 16));
      mx = fmaxf(mx, __shfl_xor(mx, 32));
      if (lg == 0) sMaxW[wave][prow] = mx;
      __syncthreads();
      float mn = m_run[hf];
      #pragma unroll
      for (int w=0; w<8; ++w) mn = fmaxf(mn, sMaxW[w][prow]);
      al[hf] = __expf(m_run[hf] - mn);
      m_run[hf] = mn;
      if (wave == 0 && lg == 0) sAlpha[prow] = al[hf];
      float sum = 0.f;
      #pragma unroll
      for (int Mt=0; Mt<8; ++Mt){
        float e0 = __expf(st[Mt][0]-mn), e1 = __expf(st[Mt][1]-mn);
        float e2 = __expf(st[Mt][2]-mn), e3 = __expf(st[Mt][3]-mn);
        sum += e0+e1+e2+e3;
        unsigned mb = mball >> (Mt*4);
        unsigned w0 = ((mb&1u)? (unsigned)f2bf(e0):0u) | (((mb&2u)? (unsigned)f2bf(e1):0u)<<16);
        unsigned w1 = ((mb&4u)? (unsigned)f2bf(e2):0u) | (((mb&8u)? (unsigned)f2bf(e3):0u)<<16);
        uint2 pv = {w0, w1};
        *(uint2*)&sW[prow*1032 + wave*128 + Mt*16 + lg*4] = pv;
      }
      sum += __shfl_xor(sum, 16);
      sum += __shfl_xor(sum, 32);
      if (lg == 0) sSumW[wave][prow] = sum;
    }
    __syncthreads();
    // ---------- d update + phase B: PV MFMA with rescale ----------
    #pragma unroll
    for (int hf=0; hf<2; ++hf){
      float ts = 0.f;
      #pragma unroll
      for (int w=0; w<8; ++w) ts += sSumW[w][hf*16 + l16];
      d_run[hf] = d_run[hf]*al[hf] + ts;
    }
    floatx4 av0 = { sAlpha[lg*4+0], sAlpha[lg*4+1], sAlpha[lg*4+2], sAlpha[lg*4+3] };
    floatx4 av1 = { sAlpha[16+lg*4+0], sAlpha[16+lg*4+1], sAlpha[16+lg*4+2], sAlpha[16+lg*4+3] };
    acc00 *= av0; acc10 *= av0; acc01 *= av1; acc11 *= av1;
    int ybase = q0 >> 7;
    for (int ks=0; ks<32; ++ks){
      int kk = ks*32 + lg*8;
      int y = ybase + (kk >> 7), x8 = kk & 127;
      int gb = bbase + y*136 + x8;
      uint4 a0 = *(const uint4*)&sW[l16*1032 + kk];
      uint4 a1 = *(const uint4*)&sW[(16+l16)*1032 + kk];
      const unsigned short* p0 = b2p + gb + At0;
      uint2 b0lo = *(const uint2*)p0;
      uint2 b0hi = *(const uint2*)(p0 + 4);
      uint4 b0 = {b0lo.x, b0lo.y, b0hi.x, b0hi.y};
      const unsigned short* p1 = b2p + gb + At1;
      uint2 b1lo = *(const uint2*)p1;
      uint2 b1hi = *(const uint2*)(p1 + 4);
      uint4 b1v = {b1lo.x, b1lo.y, b1hi.x, b1hi.y};
      acc00 = mfma16(a0, b0, acc00);
      acc01 = mfma16(a1, b0, acc01);
      acc10 = mfma16(a0, b1v, acc10);
      acc11 = mfma16(a1, b1v, acc11);
    }
  }
  int pbase = ((bb*32 + pt)*8 + sp)*32;
  #pragma unroll
  for (int j=0;j<4;j++){
    int row0 = pbase + lg*4 + j;
    int row1 = pbase + 16 + lg*4 + j;
    if (f0 < F){
      pacc[(size_t)row0*F + f0] = __float2half(acc00[j]);
      pacc[(size_t)row1*F + f0] = __float2half(acc01[j]);
    }
    if (ok1 && f1 < F){
      pacc[(size_t)row0*F + f1] = __float2half(acc10[j]);
      pacc[(size_t)row1*F + f1] = __float2half(acc11[j]);
    }
  }
  if (wave == 0 && lg == 0){
    #pragma unroll
    for (int hf=0; hf<2; ++hf){
      int prow = hf*16 + l16;
      pm[pbase + prow] = m_run[hf];
      pd[pbase + prow] = d_run[hf];
    }
  }
}

// ---------------- K8: combine the 8 q-splits --------------------------------
__global__ __launch_bounds__(256) void k_combine(
    const __half* __restrict__ pacc, const float* __restrict__ pm, const float* __restrict__ pd,
    float* __restrict__ outpf){
  int i = blockIdx.x*256 + threadIdx.x;
  if (i >= 2*L*F) return;
  int f = i % F; int p = (i/F) % L; int bb = i/(F*L);
  int pt = p >> 5, r = p & 31;
  int base = ((bb*32 + pt)*8)*32 + r;
  float M = 0.f;
  #pragma unroll
  for (int hh=0; hh<NH; hh++) M = fmaxf(M, pm[base + hh*32]);
  float num = 0.f, den = 0.f;
  #pragma unroll
  for (int hh=0; hh<NH; hh++){
    float e = __expf(pm[base + hh*32] - M);
    num += e * __half2float(pacc[(size_t)(base + hh*32)*F + f]);
    den += e * pd[base + hh*32];
  }
  outpf[(size_t)(bb*L + p)*F + f] = num/den;
}

// ---------------- K9: fold + count-normalize --------------------------------
__global__ __launch_bounds__(256) void k_fold(const float* __restrict__ outpf, float* __restrict__ out){
  int i = blockIdx.x*256 + threadIdx.x;
  if (i >= 2*IC*H*W) return;
  int ww = i & 127, hh = (i>>7)&127, c = (i>>14)&3, bb = i>>16;
  int H3 = hh+3, W3 = ww+3;
  int py0 = (H3-3)>>2, py1 = min(31, H3>>2);
  int px0 = (W3-3)>>2, px1 = min(31, W3>>2);
  float s = 0.f; int cnt = 0;
  for (int py=py0; py<=py1; py++){
    int ki = H3 - 4*py;
    for (int px=px0; px<=px1; px++){
      int kj = W3 - 4*px;
      s += outpf[(size_t)((bb<<10) + py*32 + px)*F + c*49 + ki*7 + kj];
      cnt++;
    }
  }
  out[i] = s / (float)cnt;
}

extern "C" void kernel_launch(void* const* d_in, const int* in_sizes, int n_in,
                              void* d_out, int out_size, void* d_ws, size_t ws_size,
                              hipStream_t stream) {
  const float* b      = (const float*)d_in[0];
  const float* w_g    = (const float*)d_in[1];
  const float* b_g    = (const float*)d_in[2];
  const float* w_t    = (const float*)d_in[3];
  const float* b_t    = (const float*)d_in[4];
  const float* w_fc1  = (const float*)d_in[5];
  const float* b_fc1  = (const float*)d_in[6];
  const float* w_fc2  = (const float*)d_in[7];
  const float* b_fc2  = (const float*)d_in[8];
  const float* w_thr  = (const float*)d_in[9];
  const float* b_thr  = (const float*)d_in[10];
  const float* w_bias = (const float*)d_in[11];
  const float* b_bias = (const float*)d_in[12];
  float* out = (float*)d_out;
  float* ws = (float*)d_ws;

  // workspace layout (float-word offsets), total 4,504,960 words = 18.0 MB
  float* b1      = ws;                                    // 131072
  float* b2      = b1 + 131072;                           // 131072
  unsigned short* xiT = (unsigned short*)(ws + 262144);   // 4,194,304 u16 = 2,097,152 w
  unsigned short* wiP = (unsigned short*)(ws + 2359296);  // 262,144 u16 = 131,072 w
  float* meanxi  = ws + 2490368;                          // 128
  float* thr     = ws + 2490496;                          // 2048
  float* bias    = ws + 2492544;                          // 2048
  float* rowmean = ws + 2494592;                          // 2048
  unsigned short* b2p = (unsigned short*)(ws + 2496640);  // 739,840 u16 = 369,920 w
  __half* pacc   = (__half*)(ws + 2866560);               // 3,211,264 half = 1,605,632 w
  float* pm      = ws + 4472192;                          // 16384
  float* pd      = ws + 4488576;                          // 16384
  float* outpf   = ws + 262144;                           // alias xiT (dead after k_attn)
  (void)in_sizes; (void)n_in; (void)out_size; (void)ws_size;

  hipMemsetAsync(meanxi, 0, 2*G*sizeof(float), stream);
  k_front  <<<128, 256, 0, stream>>>(b, w_g, b_g, w_t, b_t, b1, b2);
  k_prep   <<<(2*B2P_PER_B + 255)/256, 256, 0, stream>>>(b2, b2p);
  k_xi     <<<256, 128, 0, stream>>>(b1, w_fc2, b_fc2, xiT, meanxi);
  k_wi     <<<(2*L*64 + 255)/256, 256, 0, stream>>>(b1, w_fc1, b_fc1, wiP);
  k_thrbias<<<256, 256, 0, stream>>>(b, w_thr, b_thr, w_bias, b_bias, thr, bias);
  k_rowmean<<<8,   256, 0, stream>>>(wiP, meanxi, rowmean);
  k_attn   <<<512, 512, 0, stream>>>(b2p, xiT, wiP, thr, bias, rowmean, pacc, pm, pd);
  k_combine<<<(2*L*F + 255)/256, 256, 0, stream>>>(pacc, pm, pd, outpf);
  k_fold   <<<512, 256, 0, stream>>>(outpf, out);
}